// Round 1
// 90.035 us; speedup vs baseline: 1.4430x; 1.4430x over previous
//
#include <hip/hip_runtime.h>

// VQ-VAE forward: out = code_out[argmax_c(logits_c(x))], hard_idx = argmax.
// logits are piecewise-linear in scalar x (128 relu breakpoints). Per
// interval, build the upper envelope of the 512 affine logit lines by an
// EXACT gift-wrapping march (fp64 cross-mul comparisons, same primitive as
// the verified pairwise version) restricted to the interval's window.
// R6/R7 lesson: in-kernel grid barriers cost 50-80us EACH on gfx950; kernel
// launch boundaries (~3us) are the cheap barrier.
// R9 (this round): O(N^2) pairwise envelope (k_env1+k_env2, ~15-20us VALU)
// replaced by O(N*H) wave-per-interval march fused into the table kernel;
// 4 launches -> 2. If dur_us does not move, the timed region is dominated
// by the harness's 3x256MiB poison fills (3x40.5us at 82% HBM peak).

#define B_SAMPLES 262144
#define HIDDEN    128
#define NUM_CODES 512
#define EMBED_DIM 256
#define NUM_INT   129     // HIDDEN + 1 intervals

// ---- workspace layout (byte offsets) ----
// 0      : t_sorted[128] double
// 2048   : code_out[512] double
// 8192   : env_cnt[129] int
// 16384  : env_xs[129*512] double   (528384 B)
// 544768 : env_idx[129*512] int     (264192 B)   -> total ~0.81 MB

__device__ __forceinline__ int classify(const double* ts, double xv) {
  int lo = 0, hi = HIDDEN;   // first index with ts[idx] > xv
  while (lo < hi) { int mid = (lo + hi) >> 1; if (ts[mid] > xv) hi = mid; else lo = mid + 1; }
  return lo;
}

// L1: blocks 0..128 = per-interval affine tables + windowed envelope march
// (wave 0); blocks 129..130 = code_out.
__global__ void __launch_bounds__(512) k_build(
    const float* __restrict__ w1, const float* __restrict__ b1,
    const float* __restrict__ w2, const float* __restrict__ b2,
    const float* __restrict__ emb, const float* __restrict__ decw,
    const float* __restrict__ decb, double* __restrict__ t_sorted,
    double* __restrict__ code_out, int* __restrict__ env_cnt,
    double* __restrict__ env_xs, int* __restrict__ env_idx) {
  const int blk = blockIdx.x, tid = threadIdx.x;
  if (blk >= NUM_INT) {                  // ---- code_out: 2 blocks x 256 codes
    __shared__ double sdw[EMBED_DIM];
    if (tid < EMBED_DIM) sdw[tid] = (double)decw[tid];
    __syncthreads();
    if (tid < 256) {
      const int c = (blk - NUM_INT) * 256 + tid;
      const float4* e4 = (const float4*)(emb + c * EMBED_DIM);
      double s = 0.0;
#pragma unroll 8
      for (int q = 0; q < EMBED_DIM / 4; ++q) {
        const float4 v = e4[q];
        const int j = q * 4;
        s = fma((double)v.x, sdw[j + 0], s);
        s = fma((double)v.y, sdw[j + 1], s);
        s = fma((double)v.z, sdw[j + 2], s);
        s = fma((double)v.w, sdw[j + 3], s);
      }
      code_out[c] = s + (double)decb[0];
    }
    return;
  }
  // ---- per-interval block ----
  __shared__ double tloc[HIDDEN], ts[HIDDEN], wj[HIDDEN], bj[HIDDEN];
  __shared__ double2 sAB[NUM_CODES];
  const int i = blk;
  if (tid < HIDDEN) {
    const double w = (double)w1[tid], b = (double)b1[tid];
    double t = -b / w;
    if (!isfinite(t)) t = 1e30;
    t = fmin(fmax(t, -1e30), 1e30);
    tloc[tid] = t;
  }
  __syncthreads();
  if (tid < HIDDEN) {                    // stable rank sort, O(128^2), ~0.5us
    const double t = tloc[tid];
    int r = 0;
    for (int k = 0; k < HIDDEN; ++k) {
      const double tk = tloc[k];
      r += (tk < t) || (tk == t && k < tid);
    }
    ts[r] = t;
  }
  __syncthreads();
  if (i == 0 && tid < HIDDEN) t_sorted[tid] = ts[tid];
  double xm;
  if (i == 0)           xm = ts[0] - 1.0;
  else if (i == HIDDEN) xm = ts[HIDDEN - 1] + 1.0;
  else                  xm = 0.5 * (ts[i - 1] + ts[i]);
  if (tid < HIDDEN) {
    const double w = (double)w1[tid], b = (double)b1[tid];
    const bool act = fma(w, xm, b) > 0.0; // relu sign constant in open interval
    wj[tid] = act ? w : 0.0;
    bj[tid] = act ? b : 0.0;
  }
  __syncthreads();
  {                                      // one code per thread: logit = A*x+B
    const int c = tid;
    const float4* r4 = (const float4*)(w2 + c * HIDDEN);
    double A = 0.0, Bv = 0.0;
#pragma unroll 8
    for (int q = 0; q < HIDDEN / 4; ++q) {
      const float4 v = r4[q];
      const int j = q * 4;
      A  = fma((double)v.x, wj[j + 0], A);
      A  = fma((double)v.y, wj[j + 1], A);
      A  = fma((double)v.z, wj[j + 2], A);
      A  = fma((double)v.w, wj[j + 3], A);
      Bv = fma((double)v.x, bj[j + 0], Bv);
      Bv = fma((double)v.y, bj[j + 1], Bv);
      Bv = fma((double)v.z, bj[j + 2], Bv);
      Bv = fma((double)v.w, bj[j + 3], Bv);
    }
    sAB[c] = make_double2(A, Bv + (double)b2[c]);
  }
  __syncthreads();
  if (tid >= 64) return;                 // wave 0 marches; others done
  const int lane = tid;
  double LA[8], LB[8];                   // 8 lines/lane, static indexing only
#pragma unroll
  for (int j = 0; j < 8; ++j) {
    const double2 ab = sAB[lane + 64 * j];
    LA[j] = ab.x;
    LB[j] = ab.y;
  }
  const bool has_lo = (i > 0), has_hi = (i < HIDDEN);
  const double xlo = ts[has_lo ? i - 1 : 0];
  const double xhi = ts[has_hi ? i : 0];

  // ---- start line: envelope line just right of the window's left edge ----
  double bA = LA[0], bB = LB[0];
  int bc = lane;
  if (!has_lo) {
    // x -> -inf: min slope, tie -> max intercept, tie -> min c (argmax-first)
#pragma unroll
    for (int j = 1; j < 8; ++j) {
      const bool t = (LA[j] < bA) || (LA[j] == bA && LB[j] > bB);
      if (t) { bA = LA[j]; bB = LB[j]; bc = lane + 64 * j; }
    }
#pragma unroll
    for (int s = 32; s; s >>= 1) {
      const double oA = __shfl_xor(bA, s), oB = __shfl_xor(bB, s);
      const int oc = __shfl_xor(bc, s);
      const bool t = (oA < bA) || (oA == bA && (oB > bB || (oB == bB && oc < bc)));
      if (t) { bA = oA; bB = oB; bc = oc; }
    }
  } else {
    // argmax at xlo via sign of fma(dA,xlo,dB); tie -> steeper, tie -> min c
#pragma unroll
    for (int j = 1; j < 8; ++j) {
      const double sg = fma(LA[j] - bA, xlo, LB[j] - bB);
      const bool t = (sg > 0.0) || (sg == 0.0 && LA[j] > bA);
      if (t) { bA = LA[j]; bB = LB[j]; bc = lane + 64 * j; }
    }
#pragma unroll
    for (int s = 32; s; s >>= 1) {
      const double oA = __shfl_xor(bA, s), oB = __shfl_xor(bB, s);
      const int oc = __shfl_xor(bc, s);
      const double sg = fma(oA - bA, xlo, oB - bB);
      const bool t = (sg > 0.0) || (sg == 0.0 && (oA > bA || (oA == bA && oc < bc)));
      if (t) { bA = oA; bB = oB; bc = oc; }
    }
  }
  bc = __shfl(bc, 0);                    // uniform state despite comparator fuzz
  double2 cur = sAB[bc];
  double Ac = cur.x, Bc = cur.y;
  const int base = i << 9;
  if (lane == 0) { env_xs[base] = -1e300; env_idx[base] = bc; }
  int r = 1;

  // ---- march: next piece = min crossing among strictly steeper lines ----
  while (r < NUM_CODES) {
    double bn = 1.0, bd = 0.0, bA2 = 0.0;  // bd==0 => invalid (x=+inf)
    int bc2 = -1;
#pragma unroll
    for (int j = 0; j < 8; ++j) {
      const double d = LA[j] - Ac;         // >0 for candidates
      const double n = Bc - LB[j];         // crossing x* = n/d
      const double l = n * bd, rr = bn * d;
      const bool t = (d > 0.0) &&
                     ((l < rr) || (l == rr && bd != 0.0 && LA[j] > bA2));
      if (t) { bn = n; bd = d; bA2 = LA[j]; bc2 = lane + 64 * j; }
    }
#pragma unroll
    for (int s = 32; s; s >>= 1) {
      const double on = __shfl_xor(bn, s), od = __shfl_xor(bd, s);
      const double oA = __shfl_xor(bA2, s);
      const int oc = __shfl_xor(bc2, s);
      bool t;
      if (bd == 0.0) t = (od != 0.0);
      else if (od == 0.0) t = false;
      else {
        const double l = on * bd, rr = bn * od;  // od,bd>0: order-preserving
        t = (l < rr) || (l == rr && (oA > bA2 || (oA == bA2 && oc < bc2)));
      }
      if (t) { bn = on; bd = od; bA2 = oA; bc2 = oc; }
    }
    const int win = __shfl(bc2, 0);
    if (win < 0) break;                  // nothing steeper: envelope done
    const double2 ab = sAB[win];
    const double d = ab.x - Ac, n = Bc - ab.y;   // exact winner line, d>0
    if (has_hi && n >= xhi * d) break;   // crossing beyond window right edge
    if (lane == 0) { env_xs[base + r] = n / d; env_idx[base + r] = win; }
    Ac = ab.x; Bc = ab.y;
    ++r;
  }
  if (lane == 0) env_cnt[i] = r;
}

// L2: per-sample lookup: 7-step LDS classify + ~3-5-step binary search in the
// interval's windowed segment table. 2 samples/thread, float2 I/O -- the two
// dependent chains interleave. xs[0] = -1e300 steers the search.
__global__ void __launch_bounds__(256) k_map(const float* __restrict__ x,
                       const double* __restrict__ t_sorted,
                       const int* __restrict__ env_cnt,
                       const double* __restrict__ env_xs,
                       const int* __restrict__ env_idx,
                       const double* __restrict__ code_out,
                       float* __restrict__ out, float* __restrict__ idx_out) {
  __shared__ double ts[HIDDEN];
  __shared__ double sco[NUM_CODES];
  __shared__ int scnt[NUM_INT];
  const int tid = threadIdx.x;
  if (tid < HIDDEN) ts[tid] = t_sorted[tid];
  if (tid < NUM_INT) scnt[tid] = env_cnt[tid];
  for (int t = tid; t < NUM_CODES; t += 256) sco[t] = code_out[t];
  __syncthreads();
  const int s = blockIdx.x * 512 + tid * 2;
  const float2 xv2 = *(const float2*)(x + s);
  const float xs2[2] = {xv2.x, xv2.y};
  float o[2], id[2];
#pragma unroll
  for (int k = 0; k < 2; ++k) {
    const double xv = (double)xs2[k];
    const int i = classify(ts, xv);
    const int base = i << 9;
    int lo = 0, hi = scnt[i] - 1;
    while (lo < hi) {                    // largest j with xs[j] <= xv
      const int mid = (lo + hi + 1) >> 1;
      if (env_xs[base + mid] <= xv) lo = mid; else hi = mid - 1;
    }
    const int ci = env_idx[base + lo];
    o[k]  = (float)sco[ci];
    id[k] = (float)ci;
  }
  *(float2*)(out + s)     = make_float2(o[0], o[1]);
  *(float2*)(idx_out + s) = make_float2(id[0], id[1]);
}

extern "C" void kernel_launch(void* const* d_in, const int* in_sizes, int n_in,
                              void* d_out, int out_size, void* d_ws, size_t ws_size,
                              hipStream_t stream) {
  const float* x    = (const float*)d_in[0];
  const float* w1   = (const float*)d_in[1];
  const float* b1   = (const float*)d_in[2];
  const float* w2   = (const float*)d_in[3];
  const float* b2   = (const float*)d_in[4];
  const float* emb  = (const float*)d_in[5];
  const float* decw = (const float*)d_in[6];
  const float* decb = (const float*)d_in[7];

  char* ws = (char*)d_ws;
  double* t_sorted = (double*)(ws + 0);
  double* code_out = (double*)(ws + 2048);
  int*    env_cnt  = (int*)   (ws + 8192);
  double* env_xs   = (double*)(ws + 16384);
  int*    env_idx  = (int*)   (ws + 544768);

  float* out  = (float*)d_out;
  float* idxo = out + B_SAMPLES;

  k_build<<<NUM_INT + 2,      512, 0, stream>>>(w1, b1, w2, b2, emb, decw, decb,
                                                t_sorted, code_out, env_cnt,
                                                env_xs, env_idx);
  k_map  <<<B_SAMPLES / 512,  256, 0, stream>>>(x, t_sorted, env_cnt, env_xs,
                                                env_idx, code_out, out, idxo);
}